// Round 9
// baseline (15149.069 us; speedup 1.0000x reference)
//
#include <hip/hip_runtime.h>
#include <math.h>

// Problem constants (match reference file)
#define BATCH 4
#define NPTS 16384
#define M 4096          // centers per cloud = RATIO * NPTS
#define MAX_NB 64
#define R2F 0.0625f     // R*R = 0.25*0.25 (exactly representable)

// FPS: ONE block per cloud, 1024 threads (16 waves, 4/SIMD).
#define FPS_T 1024
#define WPB (FPS_T / 64)          // waves per block = 16
#define PPT (NPTS / FPS_T)        // points per thread = 16

// ---------------------------------------------------------------------------
// Semantics (B): XLA-fused scan-body rounding (verified bit-exact earlier).
// ---------------------------------------------------------------------------
__device__ __forceinline__ float dist2_fma(
    float a0, float a1, float a2, float a3, float a4, float a5,
    float b0, float b1, float b2, float b3, float b4, float b5) {
  float d0 = a0 - b0;
  float s = __builtin_fmaf(d0, d0, 0.0f);
  float d1 = a1 - b1; s = __builtin_fmaf(d1, d1, s);
  float d2 = a2 - b2; s = __builtin_fmaf(d2, d2, s);
  float d3 = a3 - b3; s = __builtin_fmaf(d3, d3, s);
  float d4 = a4 - b4; s = __builtin_fmaf(d4, d4, s);
  float d5 = a5 - b5; s = __builtin_fmaf(d5, d5, s);
  return s;
}

// Semantics (A): op-by-op numpy/jnp rounding for the neighbor phase.
__device__ __forceinline__ float dist2_seq(
    float a0, float a1, float a2, float a3, float a4, float a5,
    float b0, float b1, float b2, float b3, float b4, float b5) {
#pragma clang fp contract(off)
  float d0 = a0 - b0; float s = d0 * d0;
  float d1 = a1 - b1; s = s + d1 * d1;
  float d2 = a2 - b2; s = s + d2 * d2;
  float d3 = a3 - b3; s = s + d3 * d3;
  float d4 = a4 - b4; s = s + d4 * d4;
  float d5 = a5 - b5; s = s + d5 * d5;
  return s;
}

// ---------------------------------------------------------------------------
// Kernel 1: FPS, ONE block per cloud — NO cross-block exchange.
//
// Ledger (cy/pick): R0=5430 R2=5780 R3=11000 R4=6150 R5=4546 R6=4886
// R7=4860 R8=7010. R8 POST-MORTEM: structure right (LDS exchange fine,
// deterministic), but VGPR_Count=64 — the fully-unrolled 16-iter point loop
// (80-f32 base state + 16 concurrent ds_read results/addresses/d2 chains)
// peaked >128 regs, and the allocator fell back to 64 arch regs with the
// arrays in AGPR/scratch (+VALU move per access; VALUBusy at 75% of the
// active CUs' issue at ~2.5x ideal ops — R0's failure mode, one level down).
//
// R9 = R8 with the peak pressure SHAPED under the 128-reg budget:
//   - #pragma unroll 4 on the point loop: live set = 80 base + ~4x6 temps
//     + fixed ~= 110 < 128;
//   - c4/c5 packed as one float2 LDS array (ds_read_b64, lane stride 8 B =
//     free 2-way aliasing): half the DS issues and half the live LDS
//     results of R8's two b32 reads.
//
// Per pick (zero barriers, zero global traffic):
//   1. every wave:  6-step shfl umax -> wave winner;
//                   lane0 ds_write {tag|key} -> s_wk[par][w]
//   2. ALL waves:   lane L spins s_wk[par][L&15] (monotone tag; LDS polling
//                   is banked + broadcast -> contention-free), then 4-step
//                   shfl umax over the 16 distinct slots -> cloud winner.
//
//   key = [57:46]=tag(k+1) | [45:14]=float_bits(bestv) | [13:0]=16383-idx
//
// umax == argmax with tie -> smallest index (bestv >= 0 finite so float
// bits are order-preserving; inverted idx makes max = min-index on ties).
// Max over distinct keys is associative/commutative -> reduction order
// irrelevant; dist2/update order unchanged -> picks bit-identical.
//
// Lap-safety (parity double-buffer on s_wk): wave w rewrites s_wk[par][w]
// at k+2 only after passing its iteration-(k+1) spin, which requires every
// wave's k+1 ds_write, which (program order) follows that wave's
// iteration-k spin of s_wk[par]. So an exiting spin sees exactly tag k+1.
// Write-before-spin -> no deadlock. Single 64-bit words -> relaxed
// workgroup-scope atomics suffice.
// ---------------------------------------------------------------------------
__global__
__attribute__((amdgpu_flat_work_group_size(FPS_T, FPS_T)))
__attribute__((amdgpu_waves_per_eu(4, 4)))
void fps_kernel(
    const float* __restrict__ x, const float* __restrict__ pos,
    float* __restrict__ out) {
  __shared__ float2 s_c45[NPTS];               // 128 KB: (pos.y, pos.z)
  __shared__ unsigned long long s_wk[2][WPB];  // tagged wave-winner keys

  const int b = blockIdx.x;  // cloud
  const int t = threadIdx.x;
  const int w = t >> 6;      // wave within block (0..15)
  const int lane = t & 63;

  const float* xb = x + (size_t)b * NPTS * 3;
  const float* pb = pos + (size_t)b * NPTS * 3;

  float* out_pos = out + (size_t)BATCH * M * 3;              // second output
  int* idx_stash = (int*)(out + (size_t)2 * BATCH * M * 3);  // batch region

  if (t < 2 * WPB) s_wk[t >> 4][t & (WPB - 1)] = 0ull;

  // Point state: c0-c3 + mind in registers (80 f32), (c4,c5) staged to LDS
  // as float2. Layout [p]: point p = j*1024 + t -> lane stride 8 B on
  // ds_read_b64 = free 2-way bank aliasing.
  float c0[PPT], c1[PPT], c2[PPT], c3[PPT], mind[PPT];
#pragma unroll 4
  for (int j = 0; j < PPT; ++j) {
    const int p = j * FPS_T + t;
    c0[j] = xb[3 * p + 0];
    c1[j] = xb[3 * p + 1];
    c2[j] = xb[3 * p + 2];
    c3[j] = pb[3 * p + 0];
    s_c45[p] = make_float2(pb[3 * p + 1], pb[3 * p + 2]);
    mind[j] = INFINITY;  // minimum(inf, d) == d on the first pick
  }
  __syncthreads();  // one-time: LDS init visible before the loop

  int g = 0;  // current pick (uniform; scalarized via readfirstlane)
  for (int k = 0; k < M; ++k) {
    // g is wave-uniform -> scalar center loads (L2-resident).
    const float fx0 = xb[3 * g + 0];
    const float fx1 = xb[3 * g + 1];
    const float fx2 = xb[3 * g + 2];
    const float fx3 = pb[3 * g + 0];
    const float fx4 = pb[3 * g + 1];
    const float fx5 = pb[3 * g + 2];

    if (t == 0) {
      idx_stash[b * M + k] = g;                    // for kernel 2
      out_pos[(size_t)(b * M + k) * 3 + 0] = fx3;  // pos[idx_g] (exact copy)
      out_pos[(size_t)(b * M + k) * 3 + 1] = fx4;
      out_pos[(size_t)(b * M + k) * 3 + 2] = fx5;
    }
    if (k == M - 1) break;  // last pick needs no further update/argmax

    // Min-update + per-thread (max, first-j). j ascending => p ascending, so
    // strict > keeps the earliest original index within this thread.
    // unroll 4 (not 16): caps live ds_read results/addresses so peak
    // pressure stays under the 128-reg 4-waves/EU budget (R8 lesson).
    float bestv = -1.0f;  // minds are >= 0, finite after the first update
    int bestj = 0;
#pragma unroll 4
    for (int j = 0; j < PPT; ++j) {
      const int p = j * FPS_T + t;
      const float2 a45 = s_c45[p];
      const float d2 = dist2_fma(c0[j], c1[j], c2[j], c3[j], a45.x, a45.y,
                                 fx0, fx1, fx2, fx3, fx4, fx5);
      const float nm = fminf(mind[j], d2);  // == jnp.minimum (no NaNs)
      mind[j] = nm;
      if (nm > bestv) {
        bestv = nm;
        bestj = j;
      }
    }
    const int besti = bestj * FPS_T + t;  // cloud-local point index

    // Pack and wave-reduce as u64 umax.
    unsigned long long kk =
        ((unsigned long long)__float_as_uint(bestv) << 14) |
        (unsigned long long)(unsigned)(16383 - besti);
#pragma unroll
    for (int off = 32; off > 0; off >>= 1) {
      const unsigned long long o = __shfl_xor(kk, off, 64);
      if (o > kk) kk = o;
    }

    const int par = k & 1;
    const unsigned long long want = (unsigned long long)(unsigned)(k + 1);

    // Stage 1: every wave posts its winner to its tagged LDS slot.
    if (lane == 0) {
      __hip_atomic_store(&s_wk[par][w], (want << 46) | kk, __ATOMIC_RELAXED,
                         __HIP_MEMORY_SCOPE_WORKGROUP);
    }

    // Stage 2: ALL waves spin the 16 slots (lane L -> slot L&15; 4 lanes
    // per slot = same-address broadcast, conflict-free), then 4-step shfl
    // umax within each 16-lane group -> every lane holds the cloud winner.
    unsigned long long got;
    do {
      got = __hip_atomic_load(&s_wk[par][lane & (WPB - 1)], __ATOMIC_RELAXED,
                              __HIP_MEMORY_SCOPE_WORKGROUP);
    } while ((got >> 46) < want);
#pragma unroll
    for (int off = 1; off < WPB; off <<= 1) {
      const unsigned long long o = __shfl_xor(got, off, 64);
      if (o > got) got = o;
    }
    g = __builtin_amdgcn_readfirstlane(
        16383 - (int)(got & 0x3FFFull));  // uniform -> SGPR
  }
}

// ---------------------------------------------------------------------------
// Kernel 2: radius-neighbor capped mean (verified, ~0.19 ms). Unchanged.
// ---------------------------------------------------------------------------
#define K2_T 256
__global__ __launch_bounds__(K2_T, 4) void nbr_kernel(
    const float* __restrict__ x, const float* __restrict__ pos,
    float* __restrict__ out) {
  const int lane = threadIdx.x & 63;
  const int w = threadIdx.x >> 6;
  const int cbase = blockIdx.x * 16 + w * 4;  // 4 centers per wave

  const int* idx_stash = (const int*)(out + (size_t)2 * BATCH * M * 3);
  float* out_x = out;
  float* out_batch = out + (size_t)2 * BATCH * M * 3;

  const int b = cbase / M;  // all 16 centers of a block share a cloud
  const float* xb = x + (size_t)b * NPTS * 3;
  const float* pb = pos + (size_t)b * NPTS * 3;

  float cc0[4], cc1[4], cc2[4], cc3[4], cc4[4], cc5[4];
#pragma unroll
  for (int i = 0; i < 4; ++i) {
    const int c = idx_stash[cbase + i];  // local index within cloud
    cc0[i] = xb[3 * c + 0];
    cc1[i] = xb[3 * c + 1];
    cc2[i] = xb[3 * c + 2];
    cc3[i] = pb[3 * c + 0];
    cc4[i] = pb[3 * c + 1];
    cc5[i] = pb[3 * c + 2];
  }

  float s0[4] = {0, 0, 0, 0}, s1[4] = {0, 0, 0, 0}, s2[4] = {0, 0, 0, 0};
  int cnt[4] = {0, 0, 0, 0};

  for (int p = lane; p < NPTS; p += 64) {
    const float x0 = xb[3 * p + 0];
    const float x1 = xb[3 * p + 1];
    const float x2 = xb[3 * p + 2];
    const float q0 = pb[3 * p + 0];
    const float q1 = pb[3 * p + 1];
    const float q2 = pb[3 * p + 2];
#pragma unroll
    for (int i = 0; i < 4; ++i) {
      const float d2 = dist2_seq(cc0[i], cc1[i], cc2[i], cc3[i], cc4[i],
                                 cc5[i], x0, x1, x2, q0, q1, q2);
      if (d2 <= R2F) {
        cnt[i] += 1;
        s0[i] += x0;
        s1[i] += x1;
        s2[i] += x2;
      }
    }
  }

#pragma unroll
  for (int i = 0; i < 4; ++i) {
#pragma unroll
    for (int off = 32; off > 0; off >>= 1) {
      s0[i] += __shfl_xor(s0[i], off, 64);
      s1[i] += __shfl_xor(s1[i], off, 64);
      s2[i] += __shfl_xor(s2[i], off, 64);
      cnt[i] += __shfl_xor(cnt[i], off, 64);
    }
  }

#pragma unroll
  for (int i = 0; i < 4; ++i) {
    const int total = cnt[i];
    float m0, m1, m2;
    if (total <= MAX_NB) {
      const float denom = (float)total;  // >= 1 (self is always in range)
      m0 = s0[i] / denom;
      m1 = s1[i] / denom;
      m2 = s2[i] / denom;
    } else {
      // Exact first-64-by-index fallback (wave-uniform branch, rare).
      const int base = lane * (NPTS / 64);
      int lc = 0;
      for (int p = base; p < base + NPTS / 64; ++p) {
        const float d2 =
            dist2_seq(cc0[i], cc1[i], cc2[i], cc3[i], cc4[i], cc5[i],
                      xb[3 * p + 0], xb[3 * p + 1], xb[3 * p + 2],
                      pb[3 * p + 0], pb[3 * p + 1], pb[3 * p + 2]);
        if (d2 <= R2F) lc += 1;
      }
      int pre = 0;
      for (int l = 0; l < 64; ++l) {
        const int c = __shfl(lc, l, 64);
        if (l < lane) pre += c;
      }
      float t0 = 0, t1 = 0, t2 = 0;
      int r = pre;
      for (int p = base; p < base + NPTS / 64; ++p) {
        const float x0 = xb[3 * p + 0], x1 = xb[3 * p + 1],
                    x2 = xb[3 * p + 2];
        const float d2 =
            dist2_seq(cc0[i], cc1[i], cc2[i], cc3[i], cc4[i], cc5[i], x0, x1,
                      x2, pb[3 * p + 0], pb[3 * p + 1], pb[3 * p + 2]);
        if (d2 <= R2F) {
          if (r < MAX_NB) {
            t0 += x0;
            t1 += x1;
            t2 += x2;
          }
          r += 1;
        }
      }
#pragma unroll
      for (int off = 32; off > 0; off >>= 1) {
        t0 += __shfl_xor(t0, off, 64);
        t1 += __shfl_xor(t1, off, 64);
        t2 += __shfl_xor(t2, off, 64);
      }
      m0 = t0 / 64.0f;
      m1 = t1 / 64.0f;
      m2 = t2 / 64.0f;
    }
    if (lane == i) {
      const int gc = cbase + i;
      out_x[(size_t)gc * 3 + 0] = m0;
      out_x[(size_t)gc * 3 + 1] = m1;
      out_x[(size_t)gc * 3 + 2] = m2;
      out_batch[gc] = (float)b;  // batch ids as float in the float32 buffer
    }
  }
}

extern "C" void kernel_launch(void* const* d_in, const int* in_sizes, int n_in,
                              void* d_out, int out_size, void* d_ws,
                              size_t ws_size, hipStream_t stream) {
  (void)in_sizes;
  (void)n_in;
  (void)out_size;
  (void)d_ws;
  (void)ws_size;
  const float* x = (const float*)d_in[0];
  const float* pos = (const float*)d_in[1];
  // d_in[2] (batch) is implied by the contiguous equal-size layout.
  float* out = (float*)d_out;

  fps_kernel<<<BATCH, FPS_T, 0, stream>>>(x, pos, out);
  nbr_kernel<<<(BATCH * M) / 16, K2_T, 0, stream>>>(x, pos, out);
}

// Round 10
// 13481.836 us; speedup vs baseline: 1.1237x; 1.1237x over previous
//
#include <hip/hip_runtime.h>
#include <math.h>

// Problem constants (match reference file)
#define BATCH 4
#define NPTS 16384
#define M 4096          // centers per cloud = RATIO * NPTS
#define MAX_NB 64
#define R2F 0.0625f     // R*R = 0.25*0.25 (exactly representable)

// FPS: ONE block per cloud, 1024 threads (16 waves, 4/SIMD).
#define FPS_T 1024
#define WPB (FPS_T / 64)          // waves per block = 16
#define PPT (NPTS / FPS_T)        // points per thread = 16

// ---------------------------------------------------------------------------
// Semantics (B): XLA-fused scan-body rounding (verified bit-exact earlier).
// ---------------------------------------------------------------------------
__device__ __forceinline__ float dist2_fma(
    float a0, float a1, float a2, float a3, float a4, float a5,
    float b0, float b1, float b2, float b3, float b4, float b5) {
  float d0 = a0 - b0;
  float s = __builtin_fmaf(d0, d0, 0.0f);
  float d1 = a1 - b1; s = __builtin_fmaf(d1, d1, s);
  float d2 = a2 - b2; s = __builtin_fmaf(d2, d2, s);
  float d3 = a3 - b3; s = __builtin_fmaf(d3, d3, s);
  float d4 = a4 - b4; s = __builtin_fmaf(d4, d4, s);
  float d5 = a5 - b5; s = __builtin_fmaf(d5, d5, s);
  return s;
}

// Semantics (A): op-by-op numpy/jnp rounding for the neighbor phase.
__device__ __forceinline__ float dist2_seq(
    float a0, float a1, float a2, float a3, float a4, float a5,
    float b0, float b1, float b2, float b3, float b4, float b5) {
#pragma clang fp contract(off)
  float d0 = a0 - b0; float s = d0 * d0;
  float d1 = a1 - b1; s = s + d1 * d1;
  float d2 = a2 - b2; s = s + d2 * d2;
  float d3 = a3 - b3; s = s + d3 * d3;
  float d4 = a4 - b4; s = s + d4 * d4;
  float d5 = a5 - b5; s = s + d5 * d5;
  return s;
}

// ---------------------------------------------------------------------------
// Kernel 1: FPS, ONE block per cloud — NO cross-block exchange.
//
// Ledger (cy/pick): R0=5430 R2=5780 R3=11000 R4=6150 R5=4546 R6=4886
// R7=4860 R8=7010 R9=8750.
// R8: full unroll, static indices, but the scheduler hoisted all 16
//     ds_reads -> peak pressure >128 -> arrays fell to AGPRs (VGPR=64,
//     ~96 v_accvgpr moves/wave/pick).
// R9: `#pragma unroll 4` made the induction variable RUNTIME -> runtime-
//     indexed arrays cannot live in registers at all (VGPR=52, worse).
// R10: full STATIC unroll (macro-expanded, compile-time indices) +
//     __builtin_amdgcn_sched_barrier(0) after every 4 iterations — the
//     fence stops cross-group ds_read hoisting, capping live LDS results
//     at 8 f32. Static live set: 80 (c0-c3,mind) + 6 (center) + ~12 fixed
//     + ~12 transient ~= 110 < 128 = the 4-waves/SIMD budget pinned by
//     waves_per_eu(4,4). DIAGNOSTIC: VGPR_Count 96-128 = confirmed;
//     52-64 again = allocator refuses -> revert to R5 next.
//
// Per pick (zero barriers, zero global traffic):
//   1. every wave:  6-step shfl umax -> wave winner;
//                   lane0 ds_write {tag|key} -> s_wk[par][w]
//   2. ALL waves:   lane L spins s_wk[par][L&15] (monotone tag; same-addr
//                   LDS polling is broadcast, conflict-free), then 4-step
//                   shfl umax over the 16 distinct slots -> cloud winner.
//
//   key = [57:46]=tag(k+1) | [45:14]=float_bits(bestv) | [13:0]=16383-idx
//
// umax == argmax with tie -> smallest index (bestv >= 0 finite so float
// bits are order-preserving; inverted idx makes max = min-index on ties).
// Max over distinct keys is associative/commutative -> reduction order
// irrelevant; dist2/update order unchanged -> picks bit-identical.
//
// Lap-safety (parity double-buffer on s_wk): wave w rewrites s_wk[par][w]
// at k+2 only after passing its iteration-(k+1) spin, which requires every
// wave's k+1 ds_write, which (program order) follows that wave's
// iteration-k spin of s_wk[par]. So an exiting spin sees exactly tag k+1.
// Write-before-spin -> no deadlock. Single 64-bit words -> relaxed
// workgroup-scope atomics suffice.
// ---------------------------------------------------------------------------
__global__
__attribute__((amdgpu_flat_work_group_size(FPS_T, FPS_T)))
__attribute__((amdgpu_waves_per_eu(4, 4)))
void fps_kernel(
    const float* __restrict__ x, const float* __restrict__ pos,
    float* __restrict__ out) {
  __shared__ float2 s_c45[NPTS];               // 128 KB: (pos.y, pos.z)
  __shared__ unsigned long long s_wk[2][WPB];  // tagged wave-winner keys

  const int b = blockIdx.x;  // cloud
  const int t = threadIdx.x;
  const int w = t >> 6;      // wave within block (0..15)
  const int lane = t & 63;

  const float* xb = x + (size_t)b * NPTS * 3;
  const float* pb = pos + (size_t)b * NPTS * 3;

  float* out_pos = out + (size_t)BATCH * M * 3;              // second output
  int* idx_stash = (int*)(out + (size_t)2 * BATCH * M * 3);  // batch region

  if (t < 2 * WPB) s_wk[t >> 4][t & (WPB - 1)] = 0ull;

  // Point state: c0-c3 + mind in registers (80 f32), (c4,c5) in LDS as
  // float2 (lane stride 8 B on ds_read_b64 = free 2-way bank aliasing).
  // FULLY unrolled static init (R9 lesson: partial unroll -> runtime index
  // -> arrays demoted for the whole kernel).
  float c0[PPT], c1[PPT], c2[PPT], c3[PPT], mind[PPT];
#pragma unroll
  for (int j = 0; j < PPT; ++j) {
    const int p = j * FPS_T + t;
    c0[j] = xb[3 * p + 0];
    c1[j] = xb[3 * p + 1];
    c2[j] = xb[3 * p + 2];
    c3[j] = pb[3 * p + 0];
    s_c45[p] = make_float2(pb[3 * p + 1], pb[3 * p + 2]);
    mind[j] = INFINITY;  // minimum(inf, d) == d on the first pick
  }
  __syncthreads();  // one-time: LDS init visible before the loop

// One point-iteration with a COMPILE-TIME index J (array refs stay
// register-allocatable). Grouped by sched_barrier(0) in the loop body.
#define FPS_ITER(J)                                                       \
  {                                                                       \
    const float2 a45 = s_c45[(J)*FPS_T + t];                              \
    const float d2 = dist2_fma(c0[(J)], c1[(J)], c2[(J)], c3[(J)], a45.x, \
                               a45.y, fx0, fx1, fx2, fx3, fx4, fx5);      \
    const float nm = fminf(mind[(J)], d2);                                \
    mind[(J)] = nm;                                                       \
    if (nm > bestv) {                                                     \
      bestv = nm;                                                         \
      bestj = (J);                                                        \
    }                                                                     \
  }

  int g = 0;  // current pick (uniform; scalarized via readfirstlane)
  for (int k = 0; k < M; ++k) {
    // g is wave-uniform -> scalar center loads (L2-resident).
    const float fx0 = xb[3 * g + 0];
    const float fx1 = xb[3 * g + 1];
    const float fx2 = xb[3 * g + 2];
    const float fx3 = pb[3 * g + 0];
    const float fx4 = pb[3 * g + 1];
    const float fx5 = pb[3 * g + 2];

    if (t == 0) {
      idx_stash[b * M + k] = g;                    // for kernel 2
      out_pos[(size_t)(b * M + k) * 3 + 0] = fx3;  // pos[idx_g] (exact copy)
      out_pos[(size_t)(b * M + k) * 3 + 1] = fx4;
      out_pos[(size_t)(b * M + k) * 3 + 2] = fx5;
    }
    if (k == M - 1) break;  // last pick needs no further update/argmax

    // Min-update + per-thread (max, first-j). J ascending => p ascending,
    // so strict > keeps the earliest original index within this thread.
    // sched_barrier(0) every 4 iters: caps live ds_read results at 8 f32
    // so peak pressure stays inside the 128-reg budget (R8 lesson).
    float bestv = -1.0f;  // minds are >= 0, finite after the first update
    int bestj = 0;
    FPS_ITER(0) FPS_ITER(1) FPS_ITER(2) FPS_ITER(3)
    __builtin_amdgcn_sched_barrier(0);
    FPS_ITER(4) FPS_ITER(5) FPS_ITER(6) FPS_ITER(7)
    __builtin_amdgcn_sched_barrier(0);
    FPS_ITER(8) FPS_ITER(9) FPS_ITER(10) FPS_ITER(11)
    __builtin_amdgcn_sched_barrier(0);
    FPS_ITER(12) FPS_ITER(13) FPS_ITER(14) FPS_ITER(15)
    __builtin_amdgcn_sched_barrier(0);
    const int besti = bestj * FPS_T + t;  // cloud-local point index

    // Pack and wave-reduce as u64 umax.
    unsigned long long kk =
        ((unsigned long long)__float_as_uint(bestv) << 14) |
        (unsigned long long)(unsigned)(16383 - besti);
#pragma unroll
    for (int off = 32; off > 0; off >>= 1) {
      const unsigned long long o = __shfl_xor(kk, off, 64);
      if (o > kk) kk = o;
    }

    const int par = k & 1;
    const unsigned long long want = (unsigned long long)(unsigned)(k + 1);

    // Stage 1: every wave posts its winner to its tagged LDS slot.
    if (lane == 0) {
      __hip_atomic_store(&s_wk[par][w], (want << 46) | kk, __ATOMIC_RELAXED,
                         __HIP_MEMORY_SCOPE_WORKGROUP);
    }

    // Stage 2: ALL waves spin the 16 slots (lane L -> slot L&15; 4 lanes
    // per slot = same-address broadcast, conflict-free), then 4-step shfl
    // umax within each 16-lane group -> every lane holds the cloud winner.
    unsigned long long got;
    do {
      got = __hip_atomic_load(&s_wk[par][lane & (WPB - 1)], __ATOMIC_RELAXED,
                              __HIP_MEMORY_SCOPE_WORKGROUP);
    } while ((got >> 46) < want);
#pragma unroll
    for (int off = 1; off < WPB; off <<= 1) {
      const unsigned long long o = __shfl_xor(got, off, 64);
      if (o > got) got = o;
    }
    g = __builtin_amdgcn_readfirstlane(
        16383 - (int)(got & 0x3FFFull));  // uniform -> SGPR
  }
#undef FPS_ITER
}

// ---------------------------------------------------------------------------
// Kernel 2: radius-neighbor capped mean (verified, ~0.19 ms). Unchanged.
// ---------------------------------------------------------------------------
#define K2_T 256
__global__ __launch_bounds__(K2_T, 4) void nbr_kernel(
    const float* __restrict__ x, const float* __restrict__ pos,
    float* __restrict__ out) {
  const int lane = threadIdx.x & 63;
  const int w = threadIdx.x >> 6;
  const int cbase = blockIdx.x * 16 + w * 4;  // 4 centers per wave

  const int* idx_stash = (const int*)(out + (size_t)2 * BATCH * M * 3);
  float* out_x = out;
  float* out_batch = out + (size_t)2 * BATCH * M * 3;

  const int b = cbase / M;  // all 16 centers of a block share a cloud
  const float* xb = x + (size_t)b * NPTS * 3;
  const float* pb = pos + (size_t)b * NPTS * 3;

  float cc0[4], cc1[4], cc2[4], cc3[4], cc4[4], cc5[4];
#pragma unroll
  for (int i = 0; i < 4; ++i) {
    const int c = idx_stash[cbase + i];  // local index within cloud
    cc0[i] = xb[3 * c + 0];
    cc1[i] = xb[3 * c + 1];
    cc2[i] = xb[3 * c + 2];
    cc3[i] = pb[3 * c + 0];
    cc4[i] = pb[3 * c + 1];
    cc5[i] = pb[3 * c + 2];
  }

  float s0[4] = {0, 0, 0, 0}, s1[4] = {0, 0, 0, 0}, s2[4] = {0, 0, 0, 0};
  int cnt[4] = {0, 0, 0, 0};

  for (int p = lane; p < NPTS; p += 64) {
    const float x0 = xb[3 * p + 0];
    const float x1 = xb[3 * p + 1];
    const float x2 = xb[3 * p + 2];
    const float q0 = pb[3 * p + 0];
    const float q1 = pb[3 * p + 1];
    const float q2 = pb[3 * p + 2];
#pragma unroll
    for (int i = 0; i < 4; ++i) {
      const float d2 = dist2_seq(cc0[i], cc1[i], cc2[i], cc3[i], cc4[i],
                                 cc5[i], x0, x1, x2, q0, q1, q2);
      if (d2 <= R2F) {
        cnt[i] += 1;
        s0[i] += x0;
        s1[i] += x1;
        s2[i] += x2;
      }
    }
  }

#pragma unroll
  for (int i = 0; i < 4; ++i) {
#pragma unroll
    for (int off = 32; off > 0; off >>= 1) {
      s0[i] += __shfl_xor(s0[i], off, 64);
      s1[i] += __shfl_xor(s1[i], off, 64);
      s2[i] += __shfl_xor(s2[i], off, 64);
      cnt[i] += __shfl_xor(cnt[i], off, 64);
    }
  }

#pragma unroll
  for (int i = 0; i < 4; ++i) {
    const int total = cnt[i];
    float m0, m1, m2;
    if (total <= MAX_NB) {
      const float denom = (float)total;  // >= 1 (self is always in range)
      m0 = s0[i] / denom;
      m1 = s1[i] / denom;
      m2 = s2[i] / denom;
    } else {
      // Exact first-64-by-index fallback (wave-uniform branch, rare).
      const int base = lane * (NPTS / 64);
      int lc = 0;
      for (int p = base; p < base + NPTS / 64; ++p) {
        const float d2 =
            dist2_seq(cc0[i], cc1[i], cc2[i], cc3[i], cc4[i], cc5[i],
                      xb[3 * p + 0], xb[3 * p + 1], xb[3 * p + 2],
                      pb[3 * p + 0], pb[3 * p + 1], pb[3 * p + 2]);
        if (d2 <= R2F) lc += 1;
      }
      int pre = 0;
      for (int l = 0; l < 64; ++l) {
        const int c = __shfl(lc, l, 64);
        if (l < lane) pre += c;
      }
      float t0 = 0, t1 = 0, t2 = 0;
      int r = pre;
      for (int p = base; p < base + NPTS / 64; ++p) {
        const float x0 = xb[3 * p + 0], x1 = xb[3 * p + 1],
                    x2 = xb[3 * p + 2];
        const float d2 =
            dist2_seq(cc0[i], cc1[i], cc2[i], cc3[i], cc4[i], cc5[i], x0, x1,
                      x2, pb[3 * p + 0], pb[3 * p + 1], pb[3 * p + 2]);
        if (d2 <= R2F) {
          if (r < MAX_NB) {
            t0 += x0;
            t1 += x1;
            t2 += x2;
          }
          r += 1;
        }
      }
#pragma unroll
      for (int off = 32; off > 0; off >>= 1) {
        t0 += __shfl_xor(t0, off, 64);
        t1 += __shfl_xor(t1, off, 64);
        t2 += __shfl_xor(t2, off, 64);
      }
      m0 = t0 / 64.0f;
      m1 = t1 / 64.0f;
      m2 = t2 / 64.0f;
    }
    if (lane == i) {
      const int gc = cbase + i;
      out_x[(size_t)gc * 3 + 0] = m0;
      out_x[(size_t)gc * 3 + 1] = m1;
      out_x[(size_t)gc * 3 + 2] = m2;
      out_batch[gc] = (float)b;  // batch ids as float in the float32 buffer
    }
  }
}

extern "C" void kernel_launch(void* const* d_in, const int* in_sizes, int n_in,
                              void* d_out, int out_size, void* d_ws,
                              size_t ws_size, hipStream_t stream) {
  (void)in_sizes;
  (void)n_in;
  (void)out_size;
  (void)d_ws;
  (void)ws_size;
  const float* x = (const float*)d_in[0];
  const float* pos = (const float*)d_in[1];
  // d_in[2] (batch) is implied by the contiguous equal-size layout.
  float* out = (float*)d_out;

  fps_kernel<<<BATCH, FPS_T, 0, stream>>>(x, pos, out);
  nbr_kernel<<<(BATCH * M) / 16, K2_T, 0, stream>>>(x, pos, out);
}

// Round 12
// 7971.021 us; speedup vs baseline: 1.9005x; 1.6914x over previous
//
#include <hip/hip_runtime.h>
#include <math.h>

// Problem constants (match reference file)
#define BATCH 4
#define NPTS 16384
#define M 4096          // centers per cloud = RATIO * NPTS
#define MAX_NB 64
#define R2F 0.0625f     // R*R = 0.25*0.25 (exactly representable)

// FPS split: KS blocks per cloud, each owning NPTS/KS points.
#define KS 4
#define FPS_T 512                 // threads per FPS block
#define WPB (FPS_T / 64)          // waves per block = 8
#define PPB (NPTS / KS)           // points per block = 4096
#define PPT (PPB / FPS_T)         // points per thread = 8
#define SLOT_STRIDE 32            // u64s per (parity,cloud) sector = 256 B

// ---------------------------------------------------------------------------
// Semantics (B): XLA-fused scan-body rounding (verified bit-exact earlier).
// ---------------------------------------------------------------------------
__device__ __forceinline__ float dist2_fma(
    float a0, float a1, float a2, float a3, float a4, float a5,
    float b0, float b1, float b2, float b3, float b4, float b5) {
  float d0 = a0 - b0;
  float s = __builtin_fmaf(d0, d0, 0.0f);
  float d1 = a1 - b1; s = __builtin_fmaf(d1, d1, s);
  float d2 = a2 - b2; s = __builtin_fmaf(d2, d2, s);
  float d3 = a3 - b3; s = __builtin_fmaf(d3, d3, s);
  float d4 = a4 - b4; s = __builtin_fmaf(d4, d4, s);
  float d5 = a5 - b5; s = __builtin_fmaf(d5, d5, s);
  return s;
}

// Semantics (A): op-by-op numpy/jnp rounding for the neighbor phase.
__device__ __forceinline__ float dist2_seq(
    float a0, float a1, float a2, float a3, float a4, float a5,
    float b0, float b1, float b2, float b3, float b4, float b5) {
#pragma clang fp contract(off)
  float d0 = a0 - b0; float s = d0 * d0;
  float d1 = a1 - b1; s = s + d1 * d1;
  float d2 = a2 - b2; s = s + d2 * d2;
  float d3 = a3 - b3; s = s + d3 * d3;
  float d4 = a4 - b4; s = s + d4 * d4;
  float d5 = a5 - b5; s = s + d5 * d5;
  return s;
}

// Pipelined spin: keep one load in flight ahead of the test so discovery
// quantization drops from ~1 load-latency to ~1 issue interval. Exit value
// semantics identical to `do{v=load}while(tag<want)`; the discarded
// in-flight load is harmless. Terminates: tag is monotone and the
// publisher stores before its first wait of the round (lap proof below).
#define PIPELINED_SPIN(VAR, LOADEXPR, WANT)     \
  VAR = (LOADEXPR);                             \
  for (;;) {                                    \
    const unsigned long long nx_ = (LOADEXPR);  \
    if ((VAR >> 46) >= (WANT)) break;           \
    VAR = nx_;                                  \
  }

// ---------------------------------------------------------------------------
// Kernel 1: FPS, KS=4 blocks per cloud; barrier-free; MINIMAL exchange.
// (R5 structure — best verified at 4546 cy/pick — plus pipelined spins.)
//
// Ledger (cy/pick): R0=5430 R2=5780 R3=11000 R4=6150 R5=4546 R6=4886
// R7=4860 R8=7010 R9=8750 R10=7770. R8-R10: single-block configs cannot
// keep 80-f32 arrays in arch VGPRs (allocator splits 64/64 with AGPR
// moves) — design space closed. R6/R7: all-wave global polling costs +330.
// R5's topology is the verified optimum: 4 publishers/cloud, 4 poll lanes,
// tagged-LDS intra-block combine, LDS s_res broadcast. R11 never ran
// (infra failure) — resubmitted unchanged.
//
// Per pick:
//   1. every wave:   lane0 ds_write {tag|key} -> s_wk[par][w]
//   2. wave 0:       spin 8 LDS slots (lane L&7, monotone tag), 3-step shfl
//                    umax, lane0 stores -> sector[par][cloud][sblk]
//   3. wave 0:       lanes 0-3 poll the 4 block keys, 2-step shfl umax,
//                    lane0 posts {tag<<14|g} -> s_res[par]
//   4. all waves:    spin s_res[par] (monotone u32 compare)
//
//   key = [57:46]=tag(k+1) | [45:14]=float_bits(bestv) | [13:0]=16383-idx
//
// umax over keys == argmax with tie -> smallest index (bestv >= 0 finite so
// float bits are order-preserving; inverted idx makes max = min-index on
// ties). Distinct keys + associative/commutative max -> reduction order
// irrelevant -> picks bit-identical to the reference scan.
//
// Lap-safety (parity double-buffer on s_wk, sectors, s_res): a same-parity
// rewrite happens at k+2 and transitively requires every reader to have
// finished its iteration-k wait on that location (publish-before-poll at
// every stage) -> an exiting spin sees exactly tag k+1. No deadlock: each
// agent publishes everything it owes before its first wait of the round.
// Single-word state -> relaxed atomics suffice; 256-B padded sectors.
// ---------------------------------------------------------------------------
__global__
__attribute__((amdgpu_flat_work_group_size(FPS_T, FPS_T)))
__attribute__((amdgpu_waves_per_eu(2, 2)))
void fps_kernel(
    const float* __restrict__ x, const float* __restrict__ pos,
    float* __restrict__ out, unsigned long long* __restrict__ slots) {
  __shared__ unsigned long long s_wk[2][WPB];  // tagged wave-winner keys
  __shared__ unsigned s_res[2];                // {tag<<14 | g} per parity

  const int b = blockIdx.x & (BATCH - 1);  // cloud
  const int sblk = blockIdx.x >> 2;        // sub-block within cloud (0..KS-1)
  const int t = threadIdx.x;
  const int w = t >> 6;                    // wave within block
  const int lane = t & 63;

  const float* xb = x + (size_t)b * NPTS * 3;
  const float* pb = pos + (size_t)b * NPTS * 3;

  float* out_pos = out + (size_t)BATCH * M * 3;              // second output
  int* idx_stash = (int*)(out + (size_t)2 * BATCH * M * 3);  // batch region

  const int pbase = sblk * PPB;  // this block's point range

  if (t < 2 * WPB) s_wk[t >> 3][t & (WPB - 1)] = 0ull;
  if (t == 2 * WPB) { s_res[0] = 0u; s_res[1] = 0u; }

  // My 8 points' 6-D coords + mind, all registers (56 f32, VGPR ~88).
  float c0[PPT], c1[PPT], c2[PPT], c3[PPT], c4[PPT], c5[PPT], mind[PPT];
#pragma unroll
  for (int j = 0; j < PPT; ++j) {
    const int p = pbase + j * FPS_T + t;
    c0[j] = xb[3 * p + 0];
    c1[j] = xb[3 * p + 1];
    c2[j] = xb[3 * p + 2];
    c3[j] = pb[3 * p + 0];
    c4[j] = pb[3 * p + 1];
    c5[j] = pb[3 * p + 2];
    mind[j] = INFINITY;  // minimum(inf, d) == d on the first pick
  }
  __syncthreads();  // one-time: LDS init visible before the loop

  int g = 0;  // current pick (uniform; scalarized via readfirstlane)
  for (int k = 0; k < M; ++k) {
    // g is wave-uniform -> scalar center loads (L2-resident).
    const float fx0 = xb[3 * g + 0];
    const float fx1 = xb[3 * g + 1];
    const float fx2 = xb[3 * g + 2];
    const float fx3 = pb[3 * g + 0];
    const float fx4 = pb[3 * g + 1];
    const float fx5 = pb[3 * g + 2];

    if (sblk == 0 && t == 0) {
      idx_stash[b * M + k] = g;                    // for kernel 2
      out_pos[(size_t)(b * M + k) * 3 + 0] = fx3;  // pos[idx_g] (exact copy)
      out_pos[(size_t)(b * M + k) * 3 + 1] = fx4;
      out_pos[(size_t)(b * M + k) * 3 + 2] = fx5;
    }
    if (k == M - 1) break;  // last pick needs no further update/argmax

    // Min-update + per-thread (max, first-j). j ascending => p ascending, so
    // strict > keeps the earliest original index within this thread.
    float bestv = -1.0f;  // minds are >= 0, finite after the first update
    int bestj = 0;
#pragma unroll
    for (int j = 0; j < PPT; ++j) {
      const float d2 = dist2_fma(c0[j], c1[j], c2[j], c3[j], c4[j], c5[j],
                                 fx0, fx1, fx2, fx3, fx4, fx5);
      const float nm = fminf(mind[j], d2);  // == jnp.minimum (no NaNs)
      mind[j] = nm;
      if (nm > bestv) {
        bestv = nm;
        bestj = j;
      }
    }
    const int besti = pbase + bestj * FPS_T + t;  // cloud-local point index

    // Pack and wave-reduce as u64 umax.
    unsigned long long kk =
        ((unsigned long long)__float_as_uint(bestv) << 14) |
        (unsigned long long)(unsigned)(16383 - besti);
#pragma unroll
    for (int off = 32; off > 0; off >>= 1) {
      const unsigned long long o = __shfl_xor(kk, off, 64);
      if (o > kk) kk = o;
    }

    const int par = k & 1;
    const unsigned long long want = (unsigned long long)(unsigned)(k + 1);
    const unsigned long long tagged = (want << 46) | kk;
    unsigned long long* sector =
        slots + (size_t)(par * BATCH + b) * SLOT_STRIDE;

    // Stage 1: every wave posts its winner to its tagged LDS slot.
    if (lane == 0) {
      __hip_atomic_store(&s_wk[par][w], tagged, __ATOMIC_RELAXED,
                         __HIP_MEMORY_SCOPE_WORKGROUP);
    }

    if (w == 0) {
      // Stage 2: combine the 8 wave keys (lane L spins slot L&7),
      // pipelined LDS spin, then 3-step shfl umax.
      unsigned long long got;
      PIPELINED_SPIN(
          got,
          __hip_atomic_load(&s_wk[par][lane & (WPB - 1)], __ATOMIC_RELAXED,
                            __HIP_MEMORY_SCOPE_WORKGROUP),
          want)
#pragma unroll
      for (int off = 1; off < WPB; off <<= 1) {
        const unsigned long long o = __shfl_xor(got, off, 64);
        if (o > got) got = o;
      }
      // Publish block winner to this (parity,cloud) 256-B sector.
      if (lane == 0) {
        __hip_atomic_store(&sector[sblk], got, __ATOMIC_RELAXED,
                           __HIP_MEMORY_SCOPE_AGENT);
      }
      // Stage 3: lanes 0-3 poll the 4 block keys (one 32-B group),
      // pipelined global spin.
      unsigned long long cw = got;
      if (lane < KS) {
        unsigned long long o;
        PIPELINED_SPIN(
            o,
            __hip_atomic_load(&sector[lane], __ATOMIC_RELAXED,
                              __HIP_MEMORY_SCOPE_AGENT),
            want)
        if (o > cw) cw = o;
      }
#pragma unroll
      for (int off = 1; off < KS; off <<= 1) {
        const unsigned long long o = __shfl_xor(cw, off, 64);
        if (o > cw) cw = o;
      }
      if (lane == 0) {
        const unsigned word = ((unsigned)(k + 1) << 14) |
                              (unsigned)(16383u - (unsigned)(cw & 0x3FFFull));
        __hip_atomic_store(&s_res[par], word, __ATOMIC_RELAXED,
                           __HIP_MEMORY_SCOPE_WORKGROUP);
      }
    }

    // Stage 4: all waves pick up the result. word = tag<<14 | g is monotone
    // in tag and g < 2^14, so one unsigned compare implements "tag >= k+1"
    // (lap-proof: exit sees exactly tag k+1). Pipelined LDS spin.
    {
      const unsigned wantw = (unsigned)(k + 1) << 14;
      unsigned word = __hip_atomic_load(&s_res[par], __ATOMIC_RELAXED,
                                        __HIP_MEMORY_SCOPE_WORKGROUP);
      for (;;) {
        const unsigned nx = __hip_atomic_load(&s_res[par], __ATOMIC_RELAXED,
                                              __HIP_MEMORY_SCOPE_WORKGROUP);
        if (word >= wantw) break;
        word = nx;
      }
      g = __builtin_amdgcn_readfirstlane((int)(word & 0x3FFFu));
    }
  }
}

// ---------------------------------------------------------------------------
// Kernel 2: radius-neighbor capped mean (verified, ~0.15 ms). Unchanged.
// ---------------------------------------------------------------------------
#define K2_T 256
__global__ __launch_bounds__(K2_T, 4) void nbr_kernel(
    const float* __restrict__ x, const float* __restrict__ pos,
    float* __restrict__ out) {
  const int lane = threadIdx.x & 63;
  const int w = threadIdx.x >> 6;
  const int cbase = blockIdx.x * 16 + w * 4;  // 4 centers per wave

  const int* idx_stash = (const int*)(out + (size_t)2 * BATCH * M * 3);
  float* out_x = out;
  float* out_batch = out + (size_t)2 * BATCH * M * 3;

  const int b = cbase / M;  // all 16 centers of a block share a cloud
  const float* xb = x + (size_t)b * NPTS * 3;
  const float* pb = pos + (size_t)b * NPTS * 3;

  float cc0[4], cc1[4], cc2[4], cc3[4], cc4[4], cc5[4];
#pragma unroll
  for (int i = 0; i < 4; ++i) {
    const int c = idx_stash[cbase + i];  // local index within cloud
    cc0[i] = xb[3 * c + 0];
    cc1[i] = xb[3 * c + 1];
    cc2[i] = xb[3 * c + 2];
    cc3[i] = pb[3 * c + 0];
    cc4[i] = pb[3 * c + 1];
    cc5[i] = pb[3 * c + 2];
  }

  float s0[4] = {0, 0, 0, 0}, s1[4] = {0, 0, 0, 0}, s2[4] = {0, 0, 0, 0};
  int cnt[4] = {0, 0, 0, 0};

  for (int p = lane; p < NPTS; p += 64) {
    const float x0 = xb[3 * p + 0];
    const float x1 = xb[3 * p + 1];
    const float x2 = xb[3 * p + 2];
    const float q0 = pb[3 * p + 0];
    const float q1 = pb[3 * p + 1];
    const float q2 = pb[3 * p + 2];
#pragma unroll
    for (int i = 0; i < 4; ++i) {
      const float d2 = dist2_seq(cc0[i], cc1[i], cc2[i], cc3[i], cc4[i],
                                 cc5[i], x0, x1, x2, q0, q1, q2);
      if (d2 <= R2F) {
        cnt[i] += 1;
        s0[i] += x0;
        s1[i] += x1;
        s2[i] += x2;
      }
    }
  }

#pragma unroll
  for (int i = 0; i < 4; ++i) {
#pragma unroll
    for (int off = 32; off > 0; off >>= 1) {
      s0[i] += __shfl_xor(s0[i], off, 64);
      s1[i] += __shfl_xor(s1[i], off, 64);
      s2[i] += __shfl_xor(s2[i], off, 64);
      cnt[i] += __shfl_xor(cnt[i], off, 64);
    }
  }

#pragma unroll
  for (int i = 0; i < 4; ++i) {
    const int total = cnt[i];
    float m0, m1, m2;
    if (total <= MAX_NB) {
      const float denom = (float)total;  // >= 1 (self is always in range)
      m0 = s0[i] / denom;
      m1 = s1[i] / denom;
      m2 = s2[i] / denom;
    } else {
      // Exact first-64-by-index fallback (wave-uniform branch, rare).
      const int base = lane * (NPTS / 64);
      int lc = 0;
      for (int p = base; p < base + NPTS / 64; ++p) {
        const float d2 =
            dist2_seq(cc0[i], cc1[i], cc2[i], cc3[i], cc4[i], cc5[i],
                      xb[3 * p + 0], xb[3 * p + 1], xb[3 * p + 2],
                      pb[3 * p + 0], pb[3 * p + 1], pb[3 * p + 2]);
        if (d2 <= R2F) lc += 1;
      }
      int pre = 0;
      for (int l = 0; l < 64; ++l) {
        const int c = __shfl(lc, l, 64);
        if (l < lane) pre += c;
      }
      float t0 = 0, t1 = 0, t2 = 0;
      int r = pre;
      for (int p = base; p < base + NPTS / 64; ++p) {
        const float x0 = xb[3 * p + 0], x1 = xb[3 * p + 1],
                    x2 = xb[3 * p + 2];
        const float d2 =
            dist2_seq(cc0[i], cc1[i], cc2[i], cc3[i], cc4[i], cc5[i], x0, x1,
                      x2, pb[3 * p + 0], pb[3 * p + 1], pb[3 * p + 2]);
        if (d2 <= R2F) {
          if (r < MAX_NB) {
            t0 += x0;
            t1 += x1;
            t2 += x2;
          }
          r += 1;
        }
      }
#pragma unroll
      for (int off = 32; off > 0; off >>= 1) {
        t0 += __shfl_xor(t0, off, 64);
        t1 += __shfl_xor(t1, off, 64);
        t2 += __shfl_xor(t2, off, 64);
      }
      m0 = t0 / 64.0f;
      m1 = t1 / 64.0f;
      m2 = t2 / 64.0f;
    }
    if (lane == i) {
      const int gc = cbase + i;
      out_x[(size_t)gc * 3 + 0] = m0;
      out_x[(size_t)gc * 3 + 1] = m1;
      out_x[(size_t)gc * 3 + 2] = m2;
      out_batch[gc] = (float)b;  // batch ids as float in the float32 buffer
    }
  }
}

extern "C" void kernel_launch(void* const* d_in, const int* in_sizes, int n_in,
                              void* d_out, int out_size, void* d_ws,
                              size_t ws_size, hipStream_t stream) {
  (void)in_sizes;
  (void)n_in;
  (void)out_size;
  const float* x = (const float*)d_in[0];
  const float* pos = (const float*)d_in[1];
  // d_in[2] (batch) is implied by the contiguous equal-size layout.
  float* out = (float*)d_out;

  // Cross-block exchange sectors: [2 parities][BATCH clouds] x 256 B = 2 KiB.
  // Prefer the workspace; fall back to the head of out_x (fully overwritten
  // later by nbr_kernel; never read by fps).
  const size_t slot_bytes =
      (size_t)2 * BATCH * SLOT_STRIDE * sizeof(unsigned long long);
  unsigned long long* slots = (ws_size >= slot_bytes)
                                  ? (unsigned long long*)d_ws
                                  : (unsigned long long*)d_out;
  // Must clear every launch: stale tags from a previous run would satisfy
  // the tag-poll early and corrupt picks on graph replay.
  hipMemsetAsync(slots, 0, slot_bytes, stream);

  fps_kernel<<<BATCH * KS, FPS_T, 0, stream>>>(x, pos, out, slots);
  nbr_kernel<<<(BATCH * M) / 16, K2_T, 0, stream>>>(x, pos, out);
}